// Round 1
// baseline (1828.716 us; speedup 1.0000x reference)
//
#include <hip/hip_runtime.h>

typedef unsigned short u16;
typedef unsigned int u32;

#define SEQ 96
#define DM 512
#define NBATCH 512
#define NFREQ 49
#define CUT 16
#define MROWS (NBATCH * SEQ)  // 49152

// ---------- bf16 helpers (manual, RNE) ----------
__device__ __forceinline__ u16 f2bf(float f) {
  u32 u = __float_as_uint(f);
  u32 r = (u + 0x7fffu + ((u >> 16) & 1u)) >> 16;
  return (u16)r;
}
__device__ __forceinline__ float bf2f(u16 u) {
  return __uint_as_float(((u32)u) << 16);
}

// ---------- K1: build spectral filter matrices Fl/Fh [96x96] ----------
__global__ void build_filters_k(const float* __restrict__ w,
                                float* __restrict__ Fl, float* __restrict__ Fh) {
  int idx = blockIdx.x * 256 + threadIdx.x;
  if (idx >= SEQ * SEQ) return;
  int s = idx / SEQ, t = idx % SEQ;
  int d = s - t;
  const float scale = 1.0f / (float)SEQ;
  const float w0 = 6.283185307179586f / (float)SEQ;
  float cl = 0.f, ch = 0.f;
  for (int k = 0; k < NFREQ; k++) {
    int m = (k * d) % SEQ;
    if (m < 0) m += SEQ;
    float c = (k == 0 || k == SEQ / 2) ? 1.0f : 2.0f;
    float v = c * w[k] * cosf(w0 * (float)m) * scale;
    if (k < CUT) cl += v; else ch += v;
  }
  Fl[idx] = cl;
  Fh[idx] = ch;
}

// ---------- K2: xl = Fl @ x_b, xh = Fh @ x_b (per batch, seq-axis filter) ----------
__global__ void __launch_bounds__(256) apply_filters_k(
    const float* __restrict__ x, const float* __restrict__ Fl,
    const float* __restrict__ Fh, u16* __restrict__ xl, u16* __restrict__ xh) {
  __shared__ float xs[SEQ * 64];
  int b = blockIdx.x;
  int d0 = blockIdx.y * 64;
  const float* xb = x + (size_t)b * SEQ * DM + d0;
  for (int i = threadIdx.x; i < SEQ * 64; i += 256) {
    int s = i >> 6, d = i & 63;
    xs[i] = xb[s * DM + d];
  }
  __syncthreads();
  int d = threadIdx.x & 63;
  for (int s = threadIdx.x >> 6; s < SEQ; s += 4) {
    const float* fl = Fl + s * SEQ;
    const float* fh = Fh + s * SEQ;
    float al = 0.f, ah = 0.f;
    #pragma unroll 8
    for (int t = 0; t < SEQ; t++) {
      float xv = xs[(t << 6) + d];
      al = fmaf(fl[t], xv, al);
      ah = fmaf(fh[t], xv, ah);
    }
    size_t off = (size_t)b * SEQ * DM + (size_t)s * DM + d0 + d;
    xl[off] = f2bf(al);
    xh[off] = f2bf(ah);
  }
}

// ---------- K3: yl = xl @ Wl + bl ; yh = xh @ Wh + bh (blockIdx.z selects) ----------
// A: bf16 [M,512] row-major, B: f32 [512,512] row-major, C: bf16 [M,512]
__global__ void __launch_bounds__(256) gemm_proj_k(
    const u16* __restrict__ xl, const u16* __restrict__ xh,
    const float* __restrict__ Wl, const float* __restrict__ Wh,
    const float* __restrict__ bl, const float* __restrict__ bh,
    u16* __restrict__ yl, u16* __restrict__ yh) {
  const u16* A = blockIdx.z ? xh : xl;
  const float* B = blockIdx.z ? Wh : Wl;
  const float* bias = blockIdx.z ? bh : bl;
  u16* C = blockIdx.z ? yh : yl;

  __shared__ float As[16 * 128];
  __shared__ float Bs[16 * 128];
  int m0 = blockIdx.x * 128;
  int n0 = blockIdx.y * 128;
  int tid = threadIdx.x;
  int tx = tid & 15, ty = tid >> 4;
  int mb = ty * 8, nb = tx * 8;
  float acc[8][8] = {};

  for (int kt = 0; kt < 512; kt += 16) {
    __syncthreads();
    #pragma unroll
    for (int v = 0; v < 2; v++) {
      int c = tid + v * 256;
      int m = c >> 2, kk0 = (c & 3) << 2;
      const u32* p = (const u32*)(A + (size_t)(m0 + m) * 512 + kt + kk0);
      u32 r0 = p[0], r1 = p[1];
      As[(kk0 + 0) * 128 + m] = __uint_as_float(r0 << 16);
      As[(kk0 + 1) * 128 + m] = __uint_as_float(r0 & 0xffff0000u);
      As[(kk0 + 2) * 128 + m] = __uint_as_float(r1 << 16);
      As[(kk0 + 3) * 128 + m] = __uint_as_float(r1 & 0xffff0000u);
    }
    #pragma unroll
    for (int v = 0; v < 2; v++) {
      int c = tid + v * 256;
      int kk = c >> 5, n = (c & 31) << 2;
      float4 bv = *(const float4*)(B + (size_t)(kt + kk) * 512 + n0 + n);
      *(float4*)&Bs[kk * 128 + n] = bv;
    }
    __syncthreads();
    #pragma unroll
    for (int kk = 0; kk < 16; kk++) {
      float4 a0 = *(const float4*)&As[kk * 128 + mb];
      float4 a1 = *(const float4*)&As[kk * 128 + mb + 4];
      float4 b0 = *(const float4*)&Bs[kk * 128 + nb];
      float4 b1 = *(const float4*)&Bs[kk * 128 + nb + 4];
      float av[8] = {a0.x, a0.y, a0.z, a0.w, a1.x, a1.y, a1.z, a1.w};
      float bv[8] = {b0.x, b0.y, b0.z, b0.w, b1.x, b1.y, b1.z, b1.w};
      #pragma unroll
      for (int i = 0; i < 8; i++)
        #pragma unroll
        for (int j = 0; j < 8; j++)
          acc[i][j] = fmaf(av[i], bv[j], acc[i][j]);
    }
  }
  float bv[8];
  #pragma unroll
  for (int j = 0; j < 8; j++) bv[j] = bias[n0 + nb + j];
  #pragma unroll
  for (int i = 0; i < 8; i++) {
    size_t row = (size_t)(m0 + mb + i);
    u16* crow = C + row * 512 + n0 + nb;
    ushort4 s0, s1;
    s0.x = f2bf(acc[i][0] + bv[0]); s0.y = f2bf(acc[i][1] + bv[1]);
    s0.z = f2bf(acc[i][2] + bv[2]); s0.w = f2bf(acc[i][3] + bv[3]);
    s1.x = f2bf(acc[i][4] + bv[4]); s1.y = f2bf(acc[i][5] + bv[5]);
    s1.z = f2bf(acc[i][6] + bv[6]); s1.w = f2bf(acc[i][7] + bv[7]);
    *(ushort4*)(crow) = s0;
    *(ushort4*)(crow + 4) = s1;
  }
}

// ---------- K4: g = sigmoid(yl @ Wg[0:512] + yh @ Wg[512:1024] + bg) ----------
__global__ void __launch_bounds__(256) gemm_gate_k(
    const u16* __restrict__ yl, const u16* __restrict__ yh,
    const float* __restrict__ Wg, const float* __restrict__ bg,
    u16* __restrict__ g) {
  __shared__ float As[16 * 128];
  __shared__ float Bs[16 * 128];
  int m0 = blockIdx.x * 128;
  int n0 = blockIdx.y * 128;
  int tid = threadIdx.x;
  int tx = tid & 15, ty = tid >> 4;
  int mb = ty * 8, nb = tx * 8;
  float acc[8][8] = {};

  for (int kt = 0; kt < 1024; kt += 16) {
    const u16* A = (kt < 512) ? yl : yh;
    int ka = kt & 511;
    __syncthreads();
    #pragma unroll
    for (int v = 0; v < 2; v++) {
      int c = tid + v * 256;
      int m = c >> 2, kk0 = (c & 3) << 2;
      const u32* p = (const u32*)(A + (size_t)(m0 + m) * 512 + ka + kk0);
      u32 r0 = p[0], r1 = p[1];
      As[(kk0 + 0) * 128 + m] = __uint_as_float(r0 << 16);
      As[(kk0 + 1) * 128 + m] = __uint_as_float(r0 & 0xffff0000u);
      As[(kk0 + 2) * 128 + m] = __uint_as_float(r1 << 16);
      As[(kk0 + 3) * 128 + m] = __uint_as_float(r1 & 0xffff0000u);
    }
    #pragma unroll
    for (int v = 0; v < 2; v++) {
      int c = tid + v * 256;
      int kk = c >> 5, n = (c & 31) << 2;
      float4 bv = *(const float4*)(Wg + (size_t)(kt + kk) * 512 + n0 + n);
      *(float4*)&Bs[kk * 128 + n] = bv;
    }
    __syncthreads();
    #pragma unroll
    for (int kk = 0; kk < 16; kk++) {
      float4 a0 = *(const float4*)&As[kk * 128 + mb];
      float4 a1 = *(const float4*)&As[kk * 128 + mb + 4];
      float4 b0 = *(const float4*)&Bs[kk * 128 + nb];
      float4 b1 = *(const float4*)&Bs[kk * 128 + nb + 4];
      float av[8] = {a0.x, a0.y, a0.z, a0.w, a1.x, a1.y, a1.z, a1.w};
      float bv[8] = {b0.x, b0.y, b0.z, b0.w, b1.x, b1.y, b1.z, b1.w};
      #pragma unroll
      for (int i = 0; i < 8; i++)
        #pragma unroll
        for (int j = 0; j < 8; j++)
          acc[i][j] = fmaf(av[i], bv[j], acc[i][j]);
    }
  }
  float bv[8];
  #pragma unroll
  for (int j = 0; j < 8; j++) bv[j] = bg[n0 + nb + j];
  #pragma unroll
  for (int i = 0; i < 8; i++) {
    size_t row = (size_t)(m0 + mb + i);
    u16* crow = g + row * 512 + n0 + nb;
    ushort4 s0, s1;
    float vv[8];
    #pragma unroll
    for (int j = 0; j < 8; j++) {
      float z = acc[i][j] + bv[j];
      vv[j] = 1.0f / (1.0f + expf(-z));
    }
    s0.x = f2bf(vv[0]); s0.y = f2bf(vv[1]); s0.z = f2bf(vv[2]); s0.w = f2bf(vv[3]);
    s1.x = f2bf(vv[4]); s1.y = f2bf(vv[5]); s1.z = f2bf(vv[6]); s1.w = f2bf(vv[7]);
    *(ushort4*)(crow) = s0;
    *(ushort4*)(crow + 4) = s1;
  }
}

// ---------- K5: y = x + g*yl + (1-g)*yh ; LayerNorm(y)*gamma + beta ----------
__global__ void __launch_bounds__(256) final_ln_k(
    const float* __restrict__ x, const u16* __restrict__ yl,
    const u16* __restrict__ yh, const u16* __restrict__ g,
    const float* __restrict__ gamma, const float* __restrict__ beta,
    float* __restrict__ out) {
  __shared__ float red[8];
  int r = blockIdx.x;
  size_t base = (size_t)r * 512;
  float vv[2];
  float sum = 0.f, sumsq = 0.f;
  #pragma unroll
  for (int j = 0; j < 2; j++) {
    int e = threadIdx.x + j * 256;
    float lv = bf2f(yl[base + e]);
    float hv = bf2f(yh[base + e]);
    float gv = bf2f(g[base + e]);
    float v = x[base + e] + gv * lv + (1.f - gv) * hv;
    vv[j] = v;
    sum += v;
    sumsq += v * v;
  }
  #pragma unroll
  for (int off = 32; off; off >>= 1) {
    sum += __shfl_down(sum, off);
    sumsq += __shfl_down(sumsq, off);
  }
  int wid = threadIdx.x >> 6;
  if ((threadIdx.x & 63) == 0) {
    red[wid] = sum;
    red[4 + wid] = sumsq;
  }
  __syncthreads();
  sum = red[0] + red[1] + red[2] + red[3];
  sumsq = red[4] + red[5] + red[6] + red[7];
  float mu = sum * (1.f / 512.f);
  float var = sumsq * (1.f / 512.f) - mu * mu;
  float inv = rsqrtf(var + 1e-5f);
  #pragma unroll
  for (int j = 0; j < 2; j++) {
    int e = threadIdx.x + j * 256;
    out[base + e] = (vv[j] - mu) * inv * gamma[e] + beta[e];
  }
}

extern "C" void kernel_launch(void* const* d_in, const int* in_sizes, int n_in,
                              void* d_out, int out_size, void* d_ws, size_t ws_size,
                              hipStream_t stream) {
  const float* x     = (const float*)d_in[0];
  const float* fw    = (const float*)d_in[1];
  const float* Wl    = (const float*)d_in[2];
  const float* bl    = (const float*)d_in[3];
  const float* Wh    = (const float*)d_in[4];
  const float* bh    = (const float*)d_in[5];
  const float* Wg    = (const float*)d_in[6];
  const float* bg    = (const float*)d_in[7];
  const float* gamma = (const float*)d_in[8];
  const float* beta  = (const float*)d_in[9];
  float* out = (float*)d_out;

  char* ws = (char*)d_ws;
  float* Fl = (float*)ws;            // 96*96 f32
  float* Fh = Fl + SEQ * SEQ;        // 96*96 f32
  size_t tsz = (size_t)MROWS * 512;  // elems per [B,S,D] tensor
  u16* xl = (u16*)(ws + 128 * 1024);
  u16* xh = xl + tsz;
  u16* yl = xh + tsz;
  u16* yh = yl + tsz;
  u16* gbuf = xl;  // xl dead after proj GEMM -> reuse for gate output

  build_filters_k<<<dim3(36), dim3(256), 0, stream>>>(fw, Fl, Fh);
  apply_filters_k<<<dim3(NBATCH, DM / 64), dim3(256), 0, stream>>>(x, Fl, Fh, xl, xh);
  gemm_proj_k<<<dim3(MROWS / 128, 4, 2), dim3(256), 0, stream>>>(xl, xh, Wl, Wh, bl, bh, yl, yh);
  gemm_gate_k<<<dim3(MROWS / 128, 4), dim3(256), 0, stream>>>(yl, yh, Wg, bg, gbuf);
  final_ln_k<<<dim3(MROWS), dim3(256), 0, stream>>>(x, yl, yh, gbuf, gamma, beta, out);
}

// Round 2
// 926.547 us; speedup vs baseline: 1.9737x; 1.9737x over previous
//
#include <hip/hip_runtime.h>

typedef unsigned short u16;
typedef unsigned int u32;

#define SEQ 96
#define DM 512
#define NBATCH 512
#define NFREQ 49
#define CUT 16
#define MROWS (NBATCH * SEQ)  // 49152

typedef __attribute__((ext_vector_type(8))) short bf16x8;
typedef __attribute__((ext_vector_type(4))) float f32x4;

// ---------- bf16 helpers (manual, RNE) ----------
__device__ __forceinline__ u16 f2bf(float f) {
  u32 u = __float_as_uint(f);
  u32 r = (u + 0x7fffu + ((u >> 16) & 1u)) >> 16;
  return (u16)r;
}
__device__ __forceinline__ float bf2f(u16 u) {
  return __uint_as_float(((u32)u) << 16);
}

// async global->LDS, 16B per lane. lds ptr must be wave-uniform base.
__device__ __forceinline__ void g2l16(const void* g, void* l) {
  __builtin_amdgcn_global_load_lds(
      (const __attribute__((address_space(1))) void*)g,
      (__attribute__((address_space(3))) void*)l, 16, 0, 0);
}

// ---------- K1: build spectral filter matrices Fl/Fh [96x96] ----------
__global__ void build_filters_k(const float* __restrict__ w,
                                float* __restrict__ Fl, float* __restrict__ Fh) {
  int idx = blockIdx.x * 256 + threadIdx.x;
  if (idx >= SEQ * SEQ) return;
  int s = idx / SEQ, t = idx % SEQ;
  int d = s - t;
  const float scale = 1.0f / (float)SEQ;
  const float w0 = 6.283185307179586f / (float)SEQ;
  float cl = 0.f, ch = 0.f;
  for (int k = 0; k < NFREQ; k++) {
    int m = (k * d) % SEQ;
    if (m < 0) m += SEQ;
    float c = (k == 0 || k == SEQ / 2) ? 1.0f : 2.0f;
    float v = c * w[k] * cosf(w0 * (float)m) * scale;
    if (k < CUT) cl += v; else ch += v;
  }
  Fl[idx] = cl;
  Fh[idx] = ch;
}

// ---------- K1b: transpose fp32 [K,N] weight -> bf16 [N,K] ----------
__global__ void __launch_bounds__(256) transpose_w_k(
    const float* __restrict__ W, u16* __restrict__ Wt, int K, int N) {
  __shared__ float t[32][33];
  int k0 = blockIdx.x * 32, n0 = blockIdx.y * 32;
  int tx = threadIdx.x & 31, ty = threadIdx.x >> 5;  // ty 0..7
  #pragma unroll
  for (int r = 0; r < 32; r += 8)
    t[ty + r][tx] = W[(size_t)(k0 + ty + r) * N + n0 + tx];
  __syncthreads();
  #pragma unroll
  for (int r = 0; r < 32; r += 8)
    Wt[(size_t)(n0 + ty + r) * K + k0 + tx] = f2bf(t[tx][ty + r]);
}

// ---------- K2: xl = Fl @ x_b, xh = Fh @ x_b (per batch, seq-axis filter) ----------
__global__ void __launch_bounds__(256) apply_filters_k(
    const float* __restrict__ x, const float* __restrict__ Fl,
    const float* __restrict__ Fh, u16* __restrict__ xl, u16* __restrict__ xh) {
  __shared__ float xs[SEQ * 64];
  int b = blockIdx.x;
  int d0 = blockIdx.y * 64;
  const float* xb = x + (size_t)b * SEQ * DM + d0;
  for (int i = threadIdx.x; i < SEQ * 64; i += 256) {
    int s = i >> 6, d = i & 63;
    xs[i] = xb[s * DM + d];
  }
  __syncthreads();
  int d = threadIdx.x & 63;
  for (int s = threadIdx.x >> 6; s < SEQ; s += 4) {
    const float* fl = Fl + s * SEQ;
    const float* fh = Fh + s * SEQ;
    float al = 0.f, ah = 0.f;
    #pragma unroll 8
    for (int t = 0; t < SEQ; t++) {
      float xv = xs[(t << 6) + d];
      al = fmaf(fl[t], xv, al);
      ah = fmaf(fh[t], xv, ah);
    }
    size_t off = (size_t)b * SEQ * DM + (size_t)s * DM + d0 + d;
    xl[off] = f2bf(al);
    xh[off] = f2bf(ah);
  }
}

// ---------- MFMA GEMM: C[M,512] = A[M,K]bf16 @ Wt[512,K]bf16^T + bias ----------
// 128x128 tile, BK=32, 4 waves of 64x64 each (2x2), 16x16x32 bf16 MFMA.
// K3: proj (K=512, z selects l/h).
__global__ void __launch_bounds__(256) gemm_proj_mfma_k(
    const u16* __restrict__ xl, const u16* __restrict__ xh,
    const u16* __restrict__ Wlt, const u16* __restrict__ Wht,
    const float* __restrict__ bl, const float* __restrict__ bh,
    u16* __restrict__ yl, u16* __restrict__ yh) {
  const u16* A = blockIdx.z ? xh : xl;
  const u16* Bt = blockIdx.z ? Wht : Wlt;
  const float* bias = blockIdx.z ? bh : bl;
  u16* C = blockIdx.z ? yh : yl;

  __shared__ __align__(16) u16 As[128 * 32];
  __shared__ __align__(16) u16 Bs[128 * 32];
  const int m0 = blockIdx.x * 128;
  const int n0 = blockIdx.y * 128;
  const int tid = threadIdx.x;
  const int lane = tid & 63;
  const int w = tid >> 6;
  const int wm = w & 1, wn = w >> 1;  // 2x2 waves, each 64x64
  const int l15 = lane & 15;
  const int lq = lane >> 4;  // 0..3

  f32x4 acc[4][4] = {};

  for (int kt = 0; kt < 512; kt += 32) {
    #pragma unroll
    for (int r = 0; r < 2; r++) {
      int chunk = r * 256 + tid;      // 16B chunk id (0..511)
      int row = chunk >> 2;           // 0..127
      int ce = (chunk & 3) << 3;      // elem offset within 32-k row
      u32 lo = (u32)((r * 256 + w * 64) << 4);  // wave-uniform LDS byte base
      g2l16(A + (size_t)(m0 + row) * 512 + kt + ce, (char*)As + lo);
      g2l16(Bt + (size_t)(n0 + row) * 512 + kt + ce, (char*)Bs + lo);
    }
    __syncthreads();
    bf16x8 af[4], bf[4];
    #pragma unroll
    for (int i = 0; i < 4; i++)
      af[i] = *(const bf16x8*)&As[(wm * 64 + i * 16 + l15) * 32 + lq * 8];
    #pragma unroll
    for (int j = 0; j < 4; j++)
      bf[j] = *(const bf16x8*)&Bs[(wn * 64 + j * 16 + l15) * 32 + lq * 8];
    #pragma unroll
    for (int i = 0; i < 4; i++)
      #pragma unroll
      for (int j = 0; j < 4; j++)
        acc[i][j] = __builtin_amdgcn_mfma_f32_16x16x32_bf16(af[i], bf[j], acc[i][j], 0, 0, 0);
    __syncthreads();
  }

  #pragma unroll
  for (int j = 0; j < 4; j++) {
    int n = n0 + wn * 64 + j * 16 + l15;
    float bv = bias[n];
    #pragma unroll
    for (int i = 0; i < 4; i++) {
      int mrow = m0 + wm * 64 + i * 16 + lq * 4;
      #pragma unroll
      for (int r = 0; r < 4; r++)
        C[(size_t)(mrow + r) * 512 + n] = f2bf(acc[i][j][r] + bv);
    }
  }
}

// K4: gate (K=1024 over concat(yl,yh)), sigmoid epilogue.
__global__ void __launch_bounds__(256) gemm_gate_mfma_k(
    const u16* __restrict__ yl, const u16* __restrict__ yh,
    const u16* __restrict__ Wgt, const float* __restrict__ bg,
    u16* __restrict__ g) {
  __shared__ __align__(16) u16 As[128 * 32];
  __shared__ __align__(16) u16 Bs[128 * 32];
  const int m0 = blockIdx.x * 128;
  const int n0 = blockIdx.y * 128;
  const int tid = threadIdx.x;
  const int lane = tid & 63;
  const int w = tid >> 6;
  const int wm = w & 1, wn = w >> 1;
  const int l15 = lane & 15;
  const int lq = lane >> 4;

  f32x4 acc[4][4] = {};

  for (int kt = 0; kt < 1024; kt += 32) {
    const u16* Ak = (kt < 512) ? yl : yh;
    int ka = kt & 511;
    #pragma unroll
    for (int r = 0; r < 2; r++) {
      int chunk = r * 256 + tid;
      int row = chunk >> 2;
      int ce = (chunk & 3) << 3;
      u32 lo = (u32)((r * 256 + w * 64) << 4);
      g2l16(Ak + (size_t)(m0 + row) * 512 + ka + ce, (char*)As + lo);
      g2l16(Wgt + (size_t)(n0 + row) * 1024 + kt + ce, (char*)Bs + lo);
    }
    __syncthreads();
    bf16x8 af[4], bf[4];
    #pragma unroll
    for (int i = 0; i < 4; i++)
      af[i] = *(const bf16x8*)&As[(wm * 64 + i * 16 + l15) * 32 + lq * 8];
    #pragma unroll
    for (int j = 0; j < 4; j++)
      bf[j] = *(const bf16x8*)&Bs[(wn * 64 + j * 16 + l15) * 32 + lq * 8];
    #pragma unroll
    for (int i = 0; i < 4; i++)
      #pragma unroll
      for (int j = 0; j < 4; j++)
        acc[i][j] = __builtin_amdgcn_mfma_f32_16x16x32_bf16(af[i], bf[j], acc[i][j], 0, 0, 0);
    __syncthreads();
  }

  #pragma unroll
  for (int j = 0; j < 4; j++) {
    int n = n0 + wn * 64 + j * 16 + l15;
    float bv = bg[n];
    #pragma unroll
    for (int i = 0; i < 4; i++) {
      int mrow = m0 + wm * 64 + i * 16 + lq * 4;
      #pragma unroll
      for (int r = 0; r < 4; r++) {
        float z = acc[i][j][r] + bv;
        g[(size_t)(mrow + r) * 512 + n] = f2bf(1.0f / (1.0f + __expf(-z)));
      }
    }
  }
}

// ---------- K5: y = x + g*yl + (1-g)*yh ; LayerNorm(y)*gamma + beta ----------
__global__ void __launch_bounds__(256) final_ln_k(
    const float* __restrict__ x, const u16* __restrict__ yl,
    const u16* __restrict__ yh, const u16* __restrict__ g,
    const float* __restrict__ gamma, const float* __restrict__ beta,
    float* __restrict__ out) {
  __shared__ float red[8];
  int r = blockIdx.x;
  size_t base = (size_t)r * 512;
  float vv[2];
  float sum = 0.f, sumsq = 0.f;
  #pragma unroll
  for (int j = 0; j < 2; j++) {
    int e = threadIdx.x + j * 256;
    float lv = bf2f(yl[base + e]);
    float hv = bf2f(yh[base + e]);
    float gv = bf2f(g[base + e]);
    float v = x[base + e] + gv * lv + (1.f - gv) * hv;
    vv[j] = v;
    sum += v;
    sumsq += v * v;
  }
  #pragma unroll
  for (int off = 32; off; off >>= 1) {
    sum += __shfl_down(sum, off);
    sumsq += __shfl_down(sumsq, off);
  }
  int wid = threadIdx.x >> 6;
  if ((threadIdx.x & 63) == 0) {
    red[wid] = sum;
    red[4 + wid] = sumsq;
  }
  __syncthreads();
  sum = red[0] + red[1] + red[2] + red[3];
  sumsq = red[4] + red[5] + red[6] + red[7];
  float mu = sum * (1.f / 512.f);
  float var = sumsq * (1.f / 512.f) - mu * mu;
  float inv = rsqrtf(var + 1e-5f);
  #pragma unroll
  for (int j = 0; j < 2; j++) {
    int e = threadIdx.x + j * 256;
    out[base + e] = (vv[j] - mu) * inv * gamma[e] + beta[e];
  }
}

extern "C" void kernel_launch(void* const* d_in, const int* in_sizes, int n_in,
                              void* d_out, int out_size, void* d_ws, size_t ws_size,
                              hipStream_t stream) {
  const float* x     = (const float*)d_in[0];
  const float* fw    = (const float*)d_in[1];
  const float* Wl    = (const float*)d_in[2];
  const float* bl    = (const float*)d_in[3];
  const float* Wh    = (const float*)d_in[4];
  const float* bh    = (const float*)d_in[5];
  const float* Wg    = (const float*)d_in[6];
  const float* bg    = (const float*)d_in[7];
  const float* gamma = (const float*)d_in[8];
  const float* beta  = (const float*)d_in[9];
  float* out = (float*)d_out;

  char* ws = (char*)d_ws;
  float* Fl = (float*)ws;            // 96*96 f32
  float* Fh = Fl + SEQ * SEQ;
  u16* Wlt = (u16*)(ws + 128 * 1024);           // 512x512 bf16 (transposed [N][K])
  u16* Wht = Wlt + 512 * 512;                   // 512x512
  u16* Wgt = Wht + 512 * 512;                   // 512x1024 ([N=512][K=1024])
  size_t tsz = (size_t)MROWS * 512;
  u16* xl = Wgt + 512 * 1024;
  u16* xh = xl + tsz;
  u16* yl = xh + tsz;
  u16* yh = yl + tsz;
  u16* gbuf = xl;  // xl dead after proj GEMM -> reuse for gate output

  build_filters_k<<<dim3(36), dim3(256), 0, stream>>>(fw, Fl, Fh);
  transpose_w_k<<<dim3(16, 16), dim3(256), 0, stream>>>(Wl, Wlt, 512, 512);
  transpose_w_k<<<dim3(16, 16), dim3(256), 0, stream>>>(Wh, Wht, 512, 512);
  transpose_w_k<<<dim3(32, 16), dim3(256), 0, stream>>>(Wg, Wgt, 1024, 512);
  apply_filters_k<<<dim3(NBATCH, DM / 64), dim3(256), 0, stream>>>(x, Fl, Fh, xl, xh);
  gemm_proj_mfma_k<<<dim3(MROWS / 128, 4, 2), dim3(256), 0, stream>>>(
      xl, xh, Wlt, Wht, bl, bh, yl, yh);
  gemm_gate_mfma_k<<<dim3(MROWS / 128, 4), dim3(256), 0, stream>>>(yl, yh, Wgt, bg, gbuf);
  final_ln_k<<<dim3(MROWS), dim3(256), 0, stream>>>(x, yl, yh, gbuf, gamma, beta, out);
}

// Round 3
// 458.372 us; speedup vs baseline: 3.9896x; 2.0214x over previous
//
#include <hip/hip_runtime.h>

typedef unsigned short u16;
typedef unsigned int u32;

#define SEQ 96
#define DM 512
#define NBATCH 512
#define NFREQ 49
#define CUT 16
#define MROWS (NBATCH * SEQ)  // 49152

typedef __attribute__((ext_vector_type(8))) short bf16x8;
typedef __attribute__((ext_vector_type(4))) float f32x4;

// ---------- bf16 helpers (manual, RNE) ----------
__device__ __forceinline__ u16 f2bf(float f) {
  u32 u = __float_as_uint(f);
  u32 r = (u + 0x7fffu + ((u >> 16) & 1u)) >> 16;
  return (u16)r;
}
__device__ __forceinline__ float bf2f(u16 u) {
  return __uint_as_float(((u32)u) << 16);
}

// async global->LDS, 16B per lane. lds ptr must be wave-uniform base.
__device__ __forceinline__ void g2l16(const void* g, void* l) {
  __builtin_amdgcn_global_load_lds(
      (const __attribute__((address_space(1))) void*)g,
      (__attribute__((address_space(3))) void*)l, 16, 0, 0);
}

// ---------- K1: build spectral filter matrices Fl/Fh [96x96] bf16 ----------
__global__ void build_filters_k(const float* __restrict__ w,
                                u16* __restrict__ FlB, u16* __restrict__ FhB) {
  int idx = blockIdx.x * 256 + threadIdx.x;
  if (idx >= SEQ * SEQ) return;
  int s = idx / SEQ, t = idx % SEQ;
  int d = s - t;
  const float scale = 1.0f / (float)SEQ;
  const float w0 = 6.283185307179586f / (float)SEQ;
  float cl = 0.f, ch = 0.f;
  for (int k = 0; k < NFREQ; k++) {
    int m = (k * d) % SEQ;
    if (m < 0) m += SEQ;
    float c = (k == 0 || k == SEQ / 2) ? 1.0f : 2.0f;
    float v = c * w[k] * cosf(w0 * (float)m) * scale;
    if (k < CUT) cl += v; else ch += v;
  }
  FlB[idx] = f2bf(cl);
  FhB[idx] = f2bf(ch);
}

// ---------- K1b: transpose fp32 [K,N] weight -> bf16 [N,K] ----------
__global__ void __launch_bounds__(256) transpose_w_k(
    const float* __restrict__ W, u16* __restrict__ Wt, int K, int N) {
  __shared__ float t[32][33];
  int k0 = blockIdx.x * 32, n0 = blockIdx.y * 32;
  int tx = threadIdx.x & 31, ty = threadIdx.x >> 5;  // ty 0..7
  #pragma unroll
  for (int r = 0; r < 32; r += 8)
    t[ty + r][tx] = W[(size_t)(k0 + ty + r) * N + n0 + tx];
  __syncthreads();
  #pragma unroll
  for (int r = 0; r < 32; r += 8)
    Wt[(size_t)(n0 + ty + r) * K + k0 + tx] = f2bf(t[tx][ty + r]);
}

// ---------- K2a: xT[b][d][t] = bf16(x[b][t][d]) ----------
// grid (NBATCH, DM/64), block 256. Tile: 96 t x 64 d.
__global__ void __launch_bounds__(256) xt_k(
    const float* __restrict__ x, u16* __restrict__ xT) {
  __shared__ float xs[SEQ * 65];
  int b = blockIdx.x;
  int d0 = blockIdx.y * 64;
  const float* xb = x + (size_t)b * SEQ * DM + d0;
  // load 96x64 fp32, coalesced float4
  #pragma unroll
  for (int v = 0; v < 6; v++) {
    int c = v * 256 + threadIdx.x;   // 0..1535
    int t = c >> 4, dq = (c & 15) << 2;
    float4 f = *(const float4*)(xb + (size_t)t * DM + dq);
    xs[t * 65 + dq + 0] = f.x;
    xs[t * 65 + dq + 1] = f.y;
    xs[t * 65 + dq + 2] = f.z;
    xs[t * 65 + dq + 3] = f.w;
  }
  __syncthreads();
  // write 64 rows x 96 bf16 (48 u32 words each)
  u32* outw = (u32*)(xT + ((size_t)b * DM + d0) * SEQ);
  #pragma unroll
  for (int v = 0; v < 12; v++) {
    int c = v * 256 + threadIdx.x;   // 0..3071
    int d = c / 48, tw = c % 48;
    int t0 = tw * 2;
    u32 lo = (u32)f2bf(xs[t0 * 65 + d]);
    u32 hi = (u32)f2bf(xs[(t0 + 1) * 65 + d]);
    outw[(size_t)d * 48 + tw] = lo | (hi << 16);
  }
}

// ---------- K2b: xl[b] = Fl @ x[b], xh[b] = Fh @ x[b] via MFMA ----------
// grid (NBATCH, DM/128), block 256 (4 waves, each 32 d-cols x all 96 s-rows).
__global__ void __launch_bounds__(256) filter_mfma_k(
    const u16* __restrict__ xT, const u16* __restrict__ FlB,
    const u16* __restrict__ FhB, u16* __restrict__ xl, u16* __restrict__ xh) {
  __shared__ __align__(16) u16 lds[128 * SEQ + 2 * SEQ * SEQ];  // 61056 B
  u16* Bs = lds;                 // [128 d][96 t]
  u16* As0 = lds + 128 * SEQ;    // [2][96 s][96 t]
  int tid = threadIdx.x;
  int lane = tid & 63, w = tid >> 6;
  int b = blockIdx.x, d0 = blockIdx.y * 128;

  // stage B: 128 rows x 192B = 1536 16B-chunks
  const u16* xbase = xT + ((size_t)b * DM + d0) * SEQ;
  #pragma unroll
  for (int it = 0; it < 6; it++) {
    int c = it * 256 + tid;
    int row = c / 12, off = (c % 12) * 8;
    g2l16(xbase + (size_t)row * SEQ + off, (char*)Bs + (((it * 256 + w * 64)) << 4));
  }
  // stage A (Fl then Fh): 2 x 1152 chunks
  #pragma unroll
  for (int it = 0; it < 9; it++) {
    int c = it * 256 + tid;      // 0..2303
    const u16* src = (c < 1152) ? (FlB + c * 8) : (FhB + (c - 1152) * 8);
    g2l16(src, (char*)As0 + ((it * 256 + w * 64) << 4));
  }
  __syncthreads();

  const int l15 = lane & 15, lq = lane >> 4;
  f32x4 acc[2][6][2] = {};
  #pragma unroll
  for (int ks = 0; ks < 3; ks++) {
    int kt = ks * 32;
    bf16x8 bf[2];
    #pragma unroll
    for (int j = 0; j < 2; j++)
      bf[j] = *(const bf16x8*)&Bs[(w * 32 + j * 16 + l15) * SEQ + kt + lq * 8];
    #pragma unroll
    for (int f = 0; f < 2; f++)
      #pragma unroll
      for (int i = 0; i < 6; i++) {
        bf16x8 af = *(const bf16x8*)&As0[f * SEQ * SEQ + (i * 16 + l15) * SEQ + kt + lq * 8];
        #pragma unroll
        for (int j = 0; j < 2; j++)
          acc[f][i][j] = __builtin_amdgcn_mfma_f32_16x16x32_bf16(af, bf[j], acc[f][i][j], 0, 0, 0);
      }
  }
  // epilogue: s = i*16 + lq*4 + r, d = d0 + w*32 + j*16 + l15
  #pragma unroll
  for (int f = 0; f < 2; f++) {
    u16* dst = f ? xh : xl;
    #pragma unroll
    for (int i = 0; i < 6; i++)
      #pragma unroll
      for (int j = 0; j < 2; j++) {
        int d = d0 + w * 32 + j * 16 + l15;
        #pragma unroll
        for (int r = 0; r < 4; r++) {
          int s = i * 16 + lq * 4 + r;
          dst[((size_t)b * SEQ + s) * DM + d] = f2bf(acc[f][i][j][r]);
        }
      }
  }
}

// ---------- MFMA GEMM: C[M,512] = A[M,K]bf16 @ Wt[512,K]bf16^T + bias ----------
__global__ void __launch_bounds__(256) gemm_proj_mfma_k(
    const u16* __restrict__ xl, const u16* __restrict__ xh,
    const u16* __restrict__ Wlt, const u16* __restrict__ Wht,
    const float* __restrict__ bl, const float* __restrict__ bh,
    u16* __restrict__ yl, u16* __restrict__ yh) {
  const u16* A = blockIdx.z ? xh : xl;
  const u16* Bt = blockIdx.z ? Wht : Wlt;
  const float* bias = blockIdx.z ? bh : bl;
  u16* C = blockIdx.z ? yh : yl;

  __shared__ __align__(16) u16 As[128 * 32];
  __shared__ __align__(16) u16 Bs[128 * 32];
  const int m0 = blockIdx.x * 128;
  const int n0 = blockIdx.y * 128;
  const int tid = threadIdx.x;
  const int lane = tid & 63;
  const int w = tid >> 6;
  const int wm = w & 1, wn = w >> 1;  // 2x2 waves, each 64x64
  const int l15 = lane & 15;
  const int lq = lane >> 4;  // 0..3

  f32x4 acc[4][4] = {};

  for (int kt = 0; kt < 512; kt += 32) {
    #pragma unroll
    for (int r = 0; r < 2; r++) {
      int chunk = r * 256 + tid;      // 16B chunk id (0..511)
      int row = chunk >> 2;           // 0..127
      int ce = (chunk & 3) << 3;      // elem offset within 32-k row
      u32 lo = (u32)((r * 256 + w * 64) << 4);  // wave-uniform LDS byte base
      g2l16(A + (size_t)(m0 + row) * 512 + kt + ce, (char*)As + lo);
      g2l16(Bt + (size_t)(n0 + row) * 512 + kt + ce, (char*)Bs + lo);
    }
    __syncthreads();
    bf16x8 af[4], bf[4];
    #pragma unroll
    for (int i = 0; i < 4; i++)
      af[i] = *(const bf16x8*)&As[(wm * 64 + i * 16 + l15) * 32 + lq * 8];
    #pragma unroll
    for (int j = 0; j < 4; j++)
      bf[j] = *(const bf16x8*)&Bs[(wn * 64 + j * 16 + l15) * 32 + lq * 8];
    #pragma unroll
    for (int i = 0; i < 4; i++)
      #pragma unroll
      for (int j = 0; j < 4; j++)
        acc[i][j] = __builtin_amdgcn_mfma_f32_16x16x32_bf16(af[i], bf[j], acc[i][j], 0, 0, 0);
    __syncthreads();
  }

  #pragma unroll
  for (int j = 0; j < 4; j++) {
    int n = n0 + wn * 64 + j * 16 + l15;
    float bv = bias[n];
    #pragma unroll
    for (int i = 0; i < 4; i++) {
      int mrow = m0 + wm * 64 + i * 16 + lq * 4;
      #pragma unroll
      for (int r = 0; r < 4; r++)
        C[(size_t)(mrow + r) * 512 + n] = f2bf(acc[i][j][r] + bv);
    }
  }
}

// K4: gate (K=1024 over concat(yl,yh)), sigmoid epilogue.
__global__ void __launch_bounds__(256) gemm_gate_mfma_k(
    const u16* __restrict__ yl, const u16* __restrict__ yh,
    const u16* __restrict__ Wgt, const float* __restrict__ bg,
    u16* __restrict__ g) {
  __shared__ __align__(16) u16 As[128 * 32];
  __shared__ __align__(16) u16 Bs[128 * 32];
  const int m0 = blockIdx.x * 128;
  const int n0 = blockIdx.y * 128;
  const int tid = threadIdx.x;
  const int lane = tid & 63;
  const int w = tid >> 6;
  const int wm = w & 1, wn = w >> 1;
  const int l15 = lane & 15;
  const int lq = lane >> 4;

  f32x4 acc[4][4] = {};

  for (int kt = 0; kt < 1024; kt += 32) {
    const u16* Ak = (kt < 512) ? yl : yh;
    int ka = kt & 511;
    #pragma unroll
    for (int r = 0; r < 2; r++) {
      int chunk = r * 256 + tid;
      int row = chunk >> 2;
      int ce = (chunk & 3) << 3;
      u32 lo = (u32)((r * 256 + w * 64) << 4);
      g2l16(Ak + (size_t)(m0 + row) * 512 + ka + ce, (char*)As + lo);
      g2l16(Wgt + (size_t)(n0 + row) * 1024 + kt + ce, (char*)Bs + lo);
    }
    __syncthreads();
    bf16x8 af[4], bf[4];
    #pragma unroll
    for (int i = 0; i < 4; i++)
      af[i] = *(const bf16x8*)&As[(wm * 64 + i * 16 + l15) * 32 + lq * 8];
    #pragma unroll
    for (int j = 0; j < 4; j++)
      bf[j] = *(const bf16x8*)&Bs[(wn * 64 + j * 16 + l15) * 32 + lq * 8];
    #pragma unroll
    for (int i = 0; i < 4; i++)
      #pragma unroll
      for (int j = 0; j < 4; j++)
        acc[i][j] = __builtin_amdgcn_mfma_f32_16x16x32_bf16(af[i], bf[j], acc[i][j], 0, 0, 0);
    __syncthreads();
  }

  #pragma unroll
  for (int j = 0; j < 4; j++) {
    int n = n0 + wn * 64 + j * 16 + l15;
    float bv = bg[n];
    #pragma unroll
    for (int i = 0; i < 4; i++) {
      int mrow = m0 + wm * 64 + i * 16 + lq * 4;
      #pragma unroll
      for (int r = 0; r < 4; r++) {
        float z = acc[i][j][r] + bv;
        g[(size_t)(mrow + r) * 512 + n] = f2bf(1.0f / (1.0f + __expf(-z)));
      }
    }
  }
}

// ---------- K5: y = x + g*yl + (1-g)*yh ; LayerNorm(y)*gamma + beta ----------
__global__ void __launch_bounds__(256) final_ln_k(
    const float* __restrict__ x, const u16* __restrict__ yl,
    const u16* __restrict__ yh, const u16* __restrict__ g,
    const float* __restrict__ gamma, const float* __restrict__ beta,
    float* __restrict__ out) {
  __shared__ float red[8];
  int r = blockIdx.x;
  size_t base = (size_t)r * 512;
  float vv[2];
  float sum = 0.f, sumsq = 0.f;
  #pragma unroll
  for (int j = 0; j < 2; j++) {
    int e = threadIdx.x + j * 256;
    float lv = bf2f(yl[base + e]);
    float hv = bf2f(yh[base + e]);
    float gv = bf2f(g[base + e]);
    float v = x[base + e] + gv * lv + (1.f - gv) * hv;
    vv[j] = v;
    sum += v;
    sumsq += v * v;
  }
  #pragma unroll
  for (int off = 32; off; off >>= 1) {
    sum += __shfl_down(sum, off);
    sumsq += __shfl_down(sumsq, off);
  }
  int wid = threadIdx.x >> 6;
  if ((threadIdx.x & 63) == 0) {
    red[wid] = sum;
    red[4 + wid] = sumsq;
  }
  __syncthreads();
  sum = red[0] + red[1] + red[2] + red[3];
  sumsq = red[4] + red[5] + red[6] + red[7];
  float mu = sum * (1.f / 512.f);
  float var = sumsq * (1.f / 512.f) - mu * mu;
  float inv = rsqrtf(var + 1e-5f);
  #pragma unroll
  for (int j = 0; j < 2; j++) {
    int e = threadIdx.x + j * 256;
    out[base + e] = (vv[j] - mu) * inv * gamma[e] + beta[e];
  }
}

extern "C" void kernel_launch(void* const* d_in, const int* in_sizes, int n_in,
                              void* d_out, int out_size, void* d_ws, size_t ws_size,
                              hipStream_t stream) {
  const float* x     = (const float*)d_in[0];
  const float* fw    = (const float*)d_in[1];
  const float* Wl    = (const float*)d_in[2];
  const float* bl    = (const float*)d_in[3];
  const float* Wh    = (const float*)d_in[4];
  const float* bh    = (const float*)d_in[5];
  const float* Wg    = (const float*)d_in[6];
  const float* bg    = (const float*)d_in[7];
  const float* gamma = (const float*)d_in[8];
  const float* beta  = (const float*)d_in[9];
  float* out = (float*)d_out;

  char* ws = (char*)d_ws;
  u16* FlB = (u16*)ws;                      // 96*96 bf16
  u16* FhB = FlB + SEQ * SEQ;
  u16* Wlt = (u16*)(ws + 64 * 1024);        // 512x512 bf16 [N][K]
  u16* Wht = Wlt + 512 * 512;
  u16* Wgt = Wht + 512 * 512;               // 512x1024 [N][K]
  size_t tsz = (size_t)MROWS * 512;         // 25165824 elems
  u16* xl = (u16*)(ws + 4 * 1024 * 1024);
  u16* xh = xl + tsz;
  u16* yl = xh + tsz;
  u16* yh = yl + tsz;
  u16* xT = yl;    // [512][512][96] = exactly tsz elems; dead before proj writes yl
  u16* gbuf = xl;  // xl dead after proj GEMM -> reuse for gate output

  build_filters_k<<<dim3(36), dim3(256), 0, stream>>>(fw, FlB, FhB);
  transpose_w_k<<<dim3(16, 16), dim3(256), 0, stream>>>(Wl, Wlt, 512, 512);
  transpose_w_k<<<dim3(16, 16), dim3(256), 0, stream>>>(Wh, Wht, 512, 512);
  transpose_w_k<<<dim3(32, 16), dim3(256), 0, stream>>>(Wg, Wgt, 1024, 512);
  xt_k<<<dim3(NBATCH, DM / 64), dim3(256), 0, stream>>>(x, xT);
  filter_mfma_k<<<dim3(NBATCH, DM / 128), dim3(256), 0, stream>>>(xT, FlB, FhB, xl, xh);
  gemm_proj_mfma_k<<<dim3(MROWS / 128, 4, 2), dim3(256), 0, stream>>>(
      xl, xh, Wlt, Wht, bl, bh, yl, yh);
  gemm_gate_mfma_k<<<dim3(MROWS / 128, 4), dim3(256), 0, stream>>>(yl, yh, Wgt, bg, gbuf);
  final_ln_k<<<dim3(MROWS), dim3(256), 0, stream>>>(x, yl, yh, gbuf, gamma, beta, out);
}